// Round 13
// baseline (167.080 us; speedup 1.0000x reference)
//
#include <hip/hip_runtime.h>
#include <math.h>

#define EMB_D 64
#define MARGIN 1.0e-4f   // ref band 2.2e-5 + 2x screen dot err 1.2e-5 + key-trunc 3.1e-5, slack 1.5x

typedef float  f32x4  __attribute__((ext_vector_type(4)));
typedef short  bf16x8 __attribute__((ext_vector_type(8)));

__device__ __forceinline__ unsigned short f2bf(float f) {
    unsigned int u = __float_as_uint(f);
    return (unsigned short)((u + 0x7FFFu + ((u >> 16) & 1u)) >> 16);
}
__device__ __forceinline__ float bf2f(unsigned short h) {
    return __uint_as_float(((unsigned int)h) << 16);
}
union Pack8 { ushort u[8]; bf16x8 v; uint4 q; };
__device__ __forceinline__ bf16x8 ldbf8(const unsigned short* p) {
    union { uint4 u; bf16x8 v; } c;
    c.u = *(const uint4*)p;
    return c.v;
}

// ---------------------------------------------------------------------------
// PREP-W [r12-proven]: w -> bf16 hi/lo chunk-transposed + wsq + zero loss.
// Chunk c = kb*512 + s*128 + q*16 + r holds w row (kb*64+s*16+r), cols q*8...
// ---------------------------------------------------------------------------
__global__ __launch_bounds__(256)
void vq_prepw_kernel(const float* __restrict__ w,
                     unsigned short* __restrict__ wt_hi,
                     unsigned short* __restrict__ wt_lo,
                     float* __restrict__ wsq, float* __restrict__ loss_out,
                     int K) {
    const int i = blockIdx.x * 256 + threadIdx.x;
    if (i == 0) loss_out[0] = 0.f;
    if (i >= K * 8) return;
    const int krow = i >> 3, q = i & 7;
    const int dest = ((krow >> 6) << 9) + (((krow >> 4) & 3) << 7) + (q << 4)
                   + (krow & 15);
    const float* src = w + (size_t)krow * EMB_D + q * 8;
    Pack8 h, l;
#pragma unroll
    for (int j = 0; j < 8; ++j) {
        const float f = src[j];
        h.u[j] = f2bf(f);
        l.u[j] = f2bf(f - bf2f(h.u[j]));
    }
    ((uint4*)wt_hi)[dest] = h.q;
    ((uint4*)wt_lo)[dest] = l.q;

    if (i < K) {   // numpy-emulated fp32 sum(w_i^2)  [proven]
        const float* wr = w + (size_t)i * EMB_D;
        float r[8];
#pragma unroll
        for (int j = 0; j < 8; ++j) r[j] = __fmul_rn(wr[j], wr[j]);
#pragma unroll
        for (int t = 1; t < 8; ++t)
#pragma unroll
            for (int j = 0; j < 8; ++j)
                r[j] = __fadd_rn(r[j], __fmul_rn(wr[t * 8 + j], wr[t * 8 + j]));
        float a = __fadd_rn(__fadd_rn(r[0], r[1]), __fadd_rn(r[2], r[3]));
        float b = __fadd_rn(__fadd_rn(r[4], r[5]), __fadd_rn(r[6], r[7]));
        wsq[i] = __fadd_rn(a, b);
    }
}

// ---------------------------------------------------------------------------
// MEGA: MFMA screen (u32-key top-2) + fused pair/full exact resolution +
// gather + loss.  Screen data path = r12-proven; exact phases = r12-proven.
// Key = (bits(score+0.25) & ~1023) | k  — positive float bits are u32-order-
// monotone; lex (score,k) min == one u32 min; trunc error in MARGIN budget.
// ---------------------------------------------------------------------------
__global__ __launch_bounds__(256, 4)
void vq_mega_kernel(const float* __restrict__ x, const float* __restrict__ w,
                    const unsigned short* __restrict__ wt_hi,
                    const unsigned short* __restrict__ wt_lo,
                    const float* __restrict__ wsq, float* __restrict__ out,
                    float* __restrict__ loss_out, int K, int N, float scale) {
    const int tid  = threadIdx.x;
    const int lane = tid & 63;
    const int wave = tid >> 6;
    const int quad = lane >> 4;
    const int c16  = lane & 15;
    const int rowbase = blockIdx.x * 64 + wave * 16;

    __shared__ uint4 sh4[512];              // staged hi chunks (8 KB)
    __shared__ uint4 sl4[512];              // staged lo chunks (8 KB)
    __shared__ float wsqo[1024];            // wsq + 0.25 (screen only)
    __shared__ unsigned int U1[4][16][17], U2[4][16][17];
    __shared__ int kf[64], strow[64], k2s[64];

    // ---- A-frags: in-register x hi/lo split [r12-proven] ----
    const float* xrow = x + (size_t)(rowbase + c16) * EMB_D + quad * 8;
    Pack8 ah0, al0, ah1, al1;
#pragma unroll
    for (int j = 0; j < 8; ++j) {
        const float f0 = xrow[j];
        ah0.u[j] = f2bf(f0); al0.u[j] = f2bf(f0 - bf2f(ah0.u[j]));
        const float f1 = xrow[32 + j];
        ah1.u[j] = f2bf(f1); al1.u[j] = f2bf(f1 - bf2f(ah1.u[j]));
    }
    const bf16x8 ahi0 = ah0.v, alo0 = al0.v, ahi1 = ah1.v, alo1 = al1.v;

    {   // wsq + 0.25 -> LDS (screen-only values)
        float4 v = ((const float4*)wsq)[tid];
        v.x += 0.25f; v.y += 0.25f; v.z += 0.25f; v.w += 0.25f;
        ((float4*)wsqo)[tid] = v;
    }

    unsigned int u1[4], u2[4];
#pragma unroll
    for (int i = 0; i < 4; ++i) { u1[i] = 0xFFFFFFFFu; u2[i] = 0xFFFFFFFFu; }

    const uint4* gh = (const uint4*)wt_hi;
    const uint4* gl = (const uint4*)wt_lo;
    uint4 ph0 = gh[tid], ph1 = gh[256 + tid];
    uint4 pl0 = gl[tid], pl1 = gl[256 + tid];

    const int nseg = K >> 6;                // 16
    for (int seg = 0; seg < nseg; ++seg) {
        sh4[tid] = ph0; sh4[256 + tid] = ph1;
        sl4[tid] = pl0; sl4[256 + tid] = pl1;
        __syncthreads();
        if (seg + 1 < nseg) {
            const int b = (seg + 1) * 512;
            ph0 = gh[b + tid]; ph1 = gh[b + 256 + tid];
            pl0 = gl[b + tid]; pl1 = gl[b + 256 + tid];
        }
        const unsigned short* shp = (const unsigned short*)sh4;
        const unsigned short* slp = (const unsigned short*)sl4;

#pragma unroll
        for (int s = 0; s < 4; ++s) {
            const bf16x8 bhi0 = ldbf8(shp + (s * 128 + lane) * 8);
            const bf16x8 bhi1 = ldbf8(shp + (s * 128 + 64 + lane) * 8);
            const bf16x8 blo0 = ldbf8(slp + (s * 128 + lane) * 8);
            const bf16x8 blo1 = ldbf8(slp + (s * 128 + 64 + lane) * 8);

            f32x4 acc0 = {0.f, 0.f, 0.f, 0.f};
            f32x4 acc1 = {0.f, 0.f, 0.f, 0.f};
            acc0 = __builtin_amdgcn_mfma_f32_16x16x32_bf16(alo0, bhi0, acc0, 0, 0, 0);
            acc1 = __builtin_amdgcn_mfma_f32_16x16x32_bf16(alo1, bhi1, acc1, 0, 0, 0);
            acc0 = __builtin_amdgcn_mfma_f32_16x16x32_bf16(ahi0, blo0, acc0, 0, 0, 0);
            acc1 = __builtin_amdgcn_mfma_f32_16x16x32_bf16(ahi1, blo1, acc1, 0, 0, 0);
            acc0 = __builtin_amdgcn_mfma_f32_16x16x32_bf16(ahi0, bhi0, acc0, 0, 0, 0);
            acc1 = __builtin_amdgcn_mfma_f32_16x16x32_bf16(ahi1, bhi1, acc1, 0, 0, 0);

            const int   kk  = seg * 64 + s * 16 + c16;   // this lane's k
            const float wqo = wsqo[kk];
#pragma unroll
            for (int i = 0; i < 4; ++i) {
                const float sp  = fmaf(-2.0f, acc0[i] + acc1[i], wqo); // >0
                const unsigned int key =
                    (__float_as_uint(sp) & 0xFFFFFC00u) | (unsigned int)kk;
                const unsigned int mx = u1[i] > key ? u1[i] : key;
                u1[i] = u1[i] < key ? u1[i] : key;
                u2[i] = u2[i] < mx  ? u2[i] : mx;
            }
        }
        __syncthreads();
    }

    // ---- cross-residue merge: top-3 keys (5-op sorted insert) ----
#pragma unroll
    for (int i = 0; i < 4; ++i) {
        const int r16 = quad * 4 + i;     // acc i = row quad*4+i, col c16
        U1[wave][r16][c16] = u1[i];
        U2[wave][r16][c16] = u2[i];
    }
    __syncthreads();
    if (lane < 16) {
        unsigned int g1 = 0xFFFFFFFFu, g2 = 0xFFFFFFFFu, g3 = 0xFFFFFFFFu;
#pragma unroll
        for (int c = 0; c < 16; ++c) {
#pragma unroll
            for (int h = 0; h < 2; ++h) {
                const unsigned int key = h == 0 ? U1[wave][lane][c]
                                                : U2[wave][lane][c];
                const unsigned int a = g1 < key ? g1 : key;
                const unsigned int b = g1 < key ? key : g1;
                g1 = a;
                const unsigned int cc = g2 < b ? g2 : b;
                const unsigned int d  = g2 < b ? b : g2;
                g2 = cc;
                g3 = g3 < d ? g3 : d;
            }
        }
        const float s1f = __uint_as_float(g1 & 0xFFFFFC00u);
        const float s2f = __uint_as_float(g2 & 0xFFFFFC00u);
        const float s3f = __uint_as_float(g3 & 0xFFFFFC00u);
        const int idx = wave * 16 + lane;         // row offset in block
        kf[idx]  = (int)(g1 & 1023u);
        k2s[idx] = (int)(g2 & 1023u);
        int st = 0;
        if (s2f - s1f <= MARGIN) st = (s3f - s1f > MARGIN) ? 1 : 2;
        strow[idx] = st;
    }
    __syncthreads();

    // ---- phase 1: pair rows (r12-proven exact compare) ----
    if (tid < 64 && strow[tid] == 1) {
        const int row = blockIdx.x * 64 + tid;
        const int ka = kf[tid], kb = k2s[tid];
        const float4* xp = (const float4*)(x + (size_t)row * EMB_D);
        const float4* wa = (const float4*)(w + (size_t)ka * EMB_D);
        const float4* wb = (const float4*)(w + (size_t)kb * EMB_D);
        float r[8];
        double aa0 = 0, aa1 = 0, aa2 = 0, aa3 = 0;
        double ab0 = 0, ab1 = 0, ab2 = 0, ab3 = 0;
#pragma unroll
        for (int q = 0; q < 16; ++q) {
            const float4 xv = xp[q], va = wa[q], vb = wb[q];
            const int j = (q & 1) * 4;
            if (q < 2) {
                r[j + 0] = __fmul_rn(xv.x, xv.x);
                r[j + 1] = __fmul_rn(xv.y, xv.y);
                r[j + 2] = __fmul_rn(xv.z, xv.z);
                r[j + 3] = __fmul_rn(xv.w, xv.w);
            } else {
                r[j + 0] = __fadd_rn(r[j + 0], __fmul_rn(xv.x, xv.x));
                r[j + 1] = __fadd_rn(r[j + 1], __fmul_rn(xv.y, xv.y));
                r[j + 2] = __fadd_rn(r[j + 2], __fmul_rn(xv.z, xv.z));
                r[j + 3] = __fadd_rn(r[j + 3], __fmul_rn(xv.w, xv.w));
            }
            aa0 = fma((double)xv.x, (double)va.x, aa0);
            aa1 = fma((double)xv.y, (double)va.y, aa1);
            aa2 = fma((double)xv.z, (double)va.z, aa2);
            aa3 = fma((double)xv.w, (double)va.w, aa3);
            ab0 = fma((double)xv.x, (double)vb.x, ab0);
            ab1 = fma((double)xv.y, (double)vb.y, ab1);
            ab2 = fma((double)xv.z, (double)vb.z, ab2);
            ab3 = fma((double)xv.w, (double)vb.w, ab3);
        }
        const float xsq = __fadd_rn(
            __fadd_rn(__fadd_rn(r[0], r[1]), __fadd_rn(r[2], r[3])),
            __fadd_rn(__fadd_rn(r[4], r[5]), __fadd_rn(r[6], r[7])));
        const float mfa = (float)((aa0 + aa1) + (aa2 + aa3));
        const float mfb = (float)((ab0 + ab1) + (ab2 + ab3));
        const float sa = __fadd_rn(__fsub_rn(xsq, __fmul_rn(2.0f, mfa)), wsq[ka]);
        const float sb = __fadd_rn(__fsub_rn(xsq, __fmul_rn(2.0f, mfb)), wsq[kb]);
        int win = ka;
        if (sb < sa || (sb == sa && kb < ka)) win = kb;
        kf[tid] = win;
    }
    __syncthreads();

    // ---- phase 2: full rows (rare; r12-proven cooperative body) ----
    __shared__ float4 xs4[16];
    __shared__ float  xsqs;
    __shared__ float  ls[256];
    __shared__ int    lk[256];
    for (int i = 0; i < 64; ++i) {
        if (strow[i] != 2) continue;                  // block-uniform (LDS)
        const int row = blockIdx.x * 64 + i;
        if (tid < 16) xs4[tid] = ((const float4*)(x + (size_t)row * EMB_D))[tid];
        __syncthreads();
        if (tid == 0) {
            const float* xf = (const float*)xs4;
            float r[8];
#pragma unroll
            for (int j = 0; j < 8; ++j) r[j] = __fmul_rn(xf[j], xf[j]);
#pragma unroll
            for (int t = 1; t < 8; ++t)
#pragma unroll
                for (int j = 0; j < 8; ++j)
                    r[j] = __fadd_rn(r[j], __fmul_rn(xf[t * 8 + j], xf[t * 8 + j]));
            xsqs = __fadd_rn(
                __fadd_rn(__fadd_rn(r[0], r[1]), __fadd_rn(r[2], r[3])),
                __fadd_rn(__fadd_rn(r[4], r[5]), __fadd_rn(r[6], r[7])));
        }
        __syncthreads();
        const float xsq = xsqs;

        float bs = INFINITY;
        int   bk = K;
        for (int t = 0; t < 4; ++t) {
            const int k = wave * (K >> 2) + t * 64 + lane;
            const float4* wr4 = (const float4*)(w + (size_t)k * EMB_D);
            double a0 = 0.0, a1 = 0.0, a2 = 0.0, a3 = 0.0;
#pragma unroll
            for (int q = 0; q < EMB_D / 4; ++q) {
                const float4 xv = xs4[q];
                const float4 wv = wr4[q];
                a0 = fma((double)xv.x, (double)wv.x, a0);
                a1 = fma((double)xv.y, (double)wv.y, a1);
                a2 = fma((double)xv.z, (double)wv.z, a2);
                a3 = fma((double)xv.w, (double)wv.w, a3);
            }
            const float mf = (float)((a0 + a1) + (a2 + a3));
            const float t2 = __fsub_rn(xsq, __fmul_rn(2.0f, mf));
            const float sc = __fadd_rn(t2, wsq[k]);
            if (sc < bs || (sc == bs && k < bk)) { bs = sc; bk = k; }
        }
        ls[tid] = bs; lk[tid] = bk;
        __syncthreads();
        if (wave == 0) {
            float gs = ls[lane];
            int   gk = lk[lane];
#pragma unroll
            for (int c = 1; c < 4; ++c) {
                const float os = ls[c * 64 + lane];
                const int   ok = lk[c * 64 + lane];
                if (os < gs || (os == gs && ok < gk)) { gs = os; gk = ok; }
            }
#pragma unroll
            for (int off = 32; off > 0; off >>= 1) {
                const float os = __shfl_down(gs, off);
                const int   ok = __shfl_down(gk, off);
                if (os < gs || (os == gs && ok < gk)) { gs = os; gk = ok; }
            }
            if (lane == 0) kf[i] = gk;
        }
        __syncthreads();
    }

    // ---- phase 3: indices + gather + loss (r12-proven) ----
    if (tid < 64) {
        const int row = blockIdx.x * 64 + tid;
        out[(size_t)N * EMB_D + row] = (float)kf[tid];
    }
    float lpart = 0.f;
#pragma unroll
    for (int rep = 0; rep < 4; ++rep) {
        int f4   = rep * 256 + tid;
        int rr   = f4 >> 4;
        int c    = f4 & 15;
        int k    = kf[rr];
        int grow = blockIdx.x * 64 + rr;
        float4 wv = ((const float4*)(w + (size_t)k * EMB_D))[c];
        float4 xq = ((const float4*)(x + (size_t)grow * EMB_D))[c];
        ((float4*)out)[(size_t)grow * (EMB_D / 4) + c] = wv;
        float dx = wv.x - xq.x, dy = wv.y - xq.y;
        float dz = wv.z - xq.z, dw = wv.w - xq.w;
        lpart += dx * dx + dy * dy + dz * dz + dw * dw;
    }
#pragma unroll
    for (int off = 32; off > 0; off >>= 1) lpart += __shfl_down(lpart, off);
    __shared__ float lred[4];
    if (lane == 0) lred[wave] = lpart;
    __syncthreads();
    if (tid == 0)
        atomicAdd(loss_out, ((lred[0] + lred[1]) + (lred[2] + lred[3])) * scale);
}

extern "C" void kernel_launch(void* const* d_in, const int* in_sizes, int n_in,
                              void* d_out, int out_size, void* d_ws, size_t ws_size,
                              hipStream_t stream) {
    const float* x = (const float*)d_in[0];
    const float* w = (const float*)d_in[1];
    float* out = (float*)d_out;
    const int xsz = in_sizes[0];   // N * D
    const int wsz = in_sizes[1];   // K * D
    const int N   = xsz / EMB_D;   // 65536
    const int K   = wsz / EMB_D;   // 1024
    const int NB  = N / 64;        // 1024
    float* loss_out = out + (size_t)N * EMB_D + N;

    // ws: [wsq Kf][wt_hi K*64 u16][wt_lo K*64 u16]
    float* wsq = (float*)d_ws;
    unsigned short* wt_hi = (unsigned short*)(wsq + K);
    unsigned short* wt_lo = wt_hi + (size_t)K * EMB_D;

    vq_prepw_kernel<<<(K * 8 + 255) / 256, 256, 0, stream>>>(w, wt_hi, wt_lo,
                                                             wsq, loss_out, K);
    vq_mega_kernel<<<NB, 256, 0, stream>>>(x, w, wt_hi, wt_lo, wsq, out,
                                           loss_out, K, N, 1.25f / (float)xsz);
}